// Round 4
// baseline (1580.695 us; speedup 1.0000x reference)
//
#include <hip/hip_runtime.h>
#include <math.h>

#define RNK 10
#define NG  55          // packed lower-triangular 10x10
#define TPB 256
#define PCH_G 64        // row-chunks for fused gram+pass1; rows/chunk = 64
#define PCH_P 128       // row-chunks for pass1/pass2;     rows/chunk = 32
#define ROWS_G 64
#define ROWS_P 32
#define ITILE 16        // rows per block in final GEMM

__device__ __forceinline__ constexpr int tri(int a, int b) { return a*(a+1)/2 + b; }

// ---------------- init ----------------
__global__ void init_kernel(const float* __restrict__ Uin, const float* __restrict__ Vin,
                            const float* __restrict__ cptr,
                            float* __restrict__ Ut, float* __restrict__ Vc,
                            float* __restrict__ Gbuf, float* __restrict__ tauacc,
                            float* __restrict__ alpha, int m, int n, int qmax) {
    int idx = blockIdx.x * TPB + threadIdx.x;
    if (idx == 0) {
        float c  = *cptr;
        float A  = erff(c * 0.70710678118654752f);              // chi2_cdf(c^2, 1)
        float B  = c * 0.79788456080286536f * expf(-0.5f*c*c);
        *alpha = 0.5f*c*c*(1.0f - A) + 0.5f*(A - B);            // chi2_cdf(c^2,3)=A-B
    }
    if (idx < RNK * m) { int k = idx / m, i = idx - k*m; Ut[idx] = Uin[i*RNK + k]; }
    if (idx < RNK * n) Vc[idx] = Vin[idx];
    if (idx < (NG + 1) * qmax) Gbuf[idx] = 0.0f;
    if (idx < qmax) tauacc[idx] = 0.0f;
}

// X [m,n] -> XT [n,m], 32x32 LDS tile
__global__ void transpose_kernel(const float* __restrict__ X, float* __restrict__ XT,
                                 int m, int n) {
    __shared__ float tile[32][33];
    int bx = blockIdx.x * 32, by = blockIdx.y * 32;
    int tx = threadIdx.x, ty = threadIdx.y;  // block (32,8)
    #pragma unroll
    for (int dy = 0; dy < 32; dy += 8)
        tile[ty+dy][tx] = X[(size_t)(by+ty+dy)*n + bx + tx];
    __syncthreads();
    #pragma unroll
    for (int dy = 0; dy < 32; dy += 8)
        XT[(size_t)(bx+ty+dy)*m + by + tx] = tile[tx][ty+dy];
}

// ---------------- hubreg kernels ----------------
// Layouts: Y [p,q] (regression j fast axis), Dm [r,p], Bm [r,q].
// D rows for the block's chunk staged in LDS (broadcast reads, 2-way-free banks).

// Fused Gram + pass1(it=0). __launch_bounds__(256,4): 128-VGPR budget so the
// 55 Gram accumulators live in registers (round-3 spilled at VGPR=64).
__global__ __launch_bounds__(TPB, 4)
void gp1_kernel(const float* __restrict__ Y, const float* __restrict__ Dm,
                const float* __restrict__ Bm, const float* __restrict__ cptr,
                const float* __restrict__ sigma0,
                float* __restrict__ Gbuf, float* __restrict__ tauacc,
                int q, int p) {
    __shared__ float sD[ROWS_G][RNK];
    int i0 = blockIdx.y * ROWS_G;
    // stage D rows: coalesced (64 consecutive i per wave)
    for (int t = threadIdx.x; t < ROWS_G * RNK; t += TPB) {
        int k = t / ROWS_G, il = t - k * ROWS_G;
        sD[il][k] = Dm[k*p + i0 + il];
    }
    __syncthreads();

    int j = blockIdx.x * TPB + threadIdx.x;
    float b[RNK];
    #pragma unroll
    for (int k = 0; k < RNK; ++k) b[k] = Bm[k*q + j];
    float csg = (*cptr) * (*sigma0);
    float acc[NG];
    #pragma unroll
    for (int k = 0; k < NG; ++k) acc[k] = 0.0f;
    float cnt = 0.0f, p1 = 0.0f;
    float y[4];
    #pragma unroll
    for (int u = 0; u < 4; ++u) y[u] = Y[(size_t)(i0+u)*q + j];
    for (int g = 0; g < ROWS_G; g += 4) {
        float yn[4];
        if (g + 4 < ROWS_G) {
            #pragma unroll
            for (int u = 0; u < 4; ++u) yn[u] = Y[(size_t)(i0+g+4+u)*q + j];
        } else {
            #pragma unroll
            for (int u = 0; u < 4; ++u) yn[u] = 0.0f;
        }
        #pragma unroll
        for (int u = 0; u < 4; ++u) {
            float d[RNK];
            #pragma unroll
            for (int k = 0; k < RNK; ++k) d[k] = sD[g+u][k];
            float yv  = y[u];
            float msk = (yv != 0.0f) ? 1.0f : 0.0f;
            cnt += msk;
            float dot = 0.0f;
            #pragma unroll
            for (int k = 0; k < RNK; ++k) dot = fmaf(d[k], b[k], dot);
            float r = (yv != 0.0f) ? yv - dot : 0.0f;
            r = fminf(fmaxf(r, -csg), csg);          // psi(R/sig0)*sig0
            p1 = fmaf(r, r, p1);
            float dm[RNK];
            #pragma unroll
            for (int k = 0; k < RNK; ++k) dm[k] = msk * d[k];
            #pragma unroll
            for (int a = 0; a < RNK; ++a)
                #pragma unroll
                for (int bb = 0; bb <= a; ++bb)
                    acc[tri(a,bb)] = fmaf(dm[a], d[bb], acc[tri(a,bb)]);
        }
        #pragma unroll
        for (int u = 0; u < 4; ++u) y[u] = yn[u];
    }
    #pragma unroll
    for (int k = 0; k < NG; ++k) atomicAdd(&Gbuf[k*q + j], acc[k]);
    atomicAdd(&Gbuf[NG*q + j], cnt);
    atomicAdd(&tauacc[j], p1);
}

// Cholesky (packed, in registers) + zero rhs for the following pass2
__global__ void chol_kernel(float* __restrict__ Gbuf, float* __restrict__ rhs, int q) {
    int j = blockIdx.x * TPB + threadIdx.x;
    if (j >= q) return;
    float g[NG];
    #pragma unroll
    for (int k = 0; k < NG; ++k) g[k] = Gbuf[k*q + j];
    #pragma unroll
    for (int a = 0; a < RNK; ++a) {
        #pragma unroll
        for (int b = 0; b < a; ++b) {
            float s = g[tri(a,b)];
            #pragma unroll
            for (int k = 0; k < b; ++k) s -= g[tri(a,k)] * g[tri(b,k)];
            g[tri(a,b)] = s / g[tri(b,b)];
        }
        float s = g[tri(a,a)];
        #pragma unroll
        for (int k = 0; k < a; ++k) s -= g[tri(a,k)] * g[tri(a,k)];
        g[tri(a,a)] = sqrtf(s);
    }
    #pragma unroll
    for (int k = 0; k < NG; ++k) Gbuf[k*q + j] = g[k];
    #pragma unroll
    for (int k = 0; k < RNK; ++k) rhs[k*q + j] = 0.0f;
}

// pass1 (it=1): sum of (psi*sigma1)^2; sigma1 was stored by pass2(it=0).
__global__ __launch_bounds__(TPB, 4)
void pass1_kernel(const float* __restrict__ Y, const float* __restrict__ Dm,
                  const float* __restrict__ Bm, const float* __restrict__ sigstore,
                  const float* __restrict__ cptr, float* __restrict__ tauacc,
                  int q, int p) {
    __shared__ float sD[ROWS_P][RNK];
    int i0 = blockIdx.y * ROWS_P;
    for (int t = threadIdx.x; t < ROWS_P * RNK; t += TPB) {
        int k = t / ROWS_P, il = t - k * ROWS_P;
        sD[il][k] = Dm[k*p + i0 + il];
    }
    __syncthreads();

    int j0 = 2 * (blockIdx.x * TPB + threadIdx.x);
    float b0[RNK], b1[RNK];
    #pragma unroll
    for (int k = 0; k < RNK; ++k) {
        float2 bv = *(const float2*)&Bm[k*q + j0];
        b0[k] = bv.x; b1[k] = bv.y;
    }
    float c = *cptr;
    float csg0 = c * sigstore[j0], csg1 = c * sigstore[j0+1];
    float a0 = 0.0f, a1 = 0.0f;
    float2 y[4];
    #pragma unroll
    for (int u = 0; u < 4; ++u) y[u] = *(const float2*)&Y[(size_t)(i0+u)*q + j0];
    for (int g = 0; g < ROWS_P; g += 4) {
        float2 yn[4];
        if (g + 4 < ROWS_P) {
            #pragma unroll
            for (int u = 0; u < 4; ++u) yn[u] = *(const float2*)&Y[(size_t)(i0+g+4+u)*q + j0];
        } else {
            #pragma unroll
            for (int u = 0; u < 4; ++u) yn[u] = make_float2(0.0f, 0.0f);
        }
        #pragma unroll
        for (int u = 0; u < 4; ++u) {
            float dot0 = 0.0f, dot1 = 0.0f;
            #pragma unroll
            for (int k = 0; k < RNK; ++k) {
                float d = sD[g+u][k];
                dot0 = fmaf(d, b0[k], dot0);
                dot1 = fmaf(d, b1[k], dot1);
            }
            float r0 = (y[u].x != 0.0f) ? y[u].x - dot0 : 0.0f;
            float r1 = (y[u].y != 0.0f) ? y[u].y - dot1 : 0.0f;
            r0 = fminf(fmaxf(r0, -csg0), csg0);
            r1 = fminf(fmaxf(r1, -csg1), csg1);
            a0 = fmaf(r0, r0, a0);
            a1 = fmaf(r1, r1, a1);
        }
        #pragma unroll
        for (int u = 0; u < 4; ++u) y[u] = yn[u];
    }
    atomicAdd(&tauacc[j0],   a0);
    atomicAdd(&tauacc[j0+1], a1);
}

// pass2: computes sigma_new inline from tauacc (tau = sqrt(tauacc/(2*nobs*a))/sig_old,
// sigma_new = sig_old * tau^lamda), then rhs[k][j] += D[i,k]*clamp(resid,+-c*sigma_new).
// mode 0 (it=0): sig_old = *sigma0, chunk-0 stores sigma_new (pass1(it=1) reads it).
// mode 1 (it=1): sig_old = sigstore[j], no store needed.
__global__ __launch_bounds__(TPB, 4)
void pass2_kernel(const float* __restrict__ Y, const float* __restrict__ Dm,
                  const float* __restrict__ Bm, const float* __restrict__ Gbuf,
                  const float* __restrict__ tauacc, float* __restrict__ sigstore,
                  const float* __restrict__ cptr, const float* __restrict__ alphap,
                  const float* __restrict__ lamdap, const float* __restrict__ sigma0p,
                  float* __restrict__ rhs, int q, int p, int mode) {
    __shared__ float sD[ROWS_P][RNK];
    int i0 = blockIdx.y * ROWS_P;
    for (int t = threadIdx.x; t < ROWS_P * RNK; t += TPB) {
        int k = t / ROWS_P, il = t - k * ROWS_P;
        sD[il][k] = Dm[k*p + i0 + il];
    }
    __syncthreads();

    int j0 = 2 * (blockIdx.x * TPB + threadIdx.x);
    float b0[RNK], b1[RNK];
    #pragma unroll
    for (int k = 0; k < RNK; ++k) {
        float2 bv = *(const float2*)&Bm[k*q + j0];
        b0[k] = bv.x; b1[k] = bv.y;
    }
    float c = *cptr, alpha = *alphap, lam = *lamdap;
    float so0 = mode ? sigstore[j0]   : *sigma0p;
    float so1 = mode ? sigstore[j0+1] : *sigma0p;
    float nb0 = Gbuf[NG*q + j0], nb1 = Gbuf[NG*q + j0+1];
    float t0 = sqrtf(tauacc[j0]   / (2.0f * nb0 * alpha)) / so0;
    float t1 = sqrtf(tauacc[j0+1] / (2.0f * nb1 * alpha)) / so1;
    float sg0 = so0 * powf(t0, lam);
    float sg1 = so1 * powf(t1, lam);
    if (mode == 0 && blockIdx.y == 0) { sigstore[j0] = sg0; sigstore[j0+1] = sg1; }
    float csg0 = c * sg0, csg1 = c * sg1;

    float a0[RNK], a1[RNK];
    #pragma unroll
    for (int k = 0; k < RNK; ++k) { a0[k] = 0.0f; a1[k] = 0.0f; }
    float2 y[4];
    #pragma unroll
    for (int u = 0; u < 4; ++u) y[u] = *(const float2*)&Y[(size_t)(i0+u)*q + j0];
    for (int g = 0; g < ROWS_P; g += 4) {
        float2 yn[4];
        if (g + 4 < ROWS_P) {
            #pragma unroll
            for (int u = 0; u < 4; ++u) yn[u] = *(const float2*)&Y[(size_t)(i0+g+4+u)*q + j0];
        } else {
            #pragma unroll
            for (int u = 0; u < 4; ++u) yn[u] = make_float2(0.0f, 0.0f);
        }
        #pragma unroll
        for (int u = 0; u < 4; ++u) {
            float d[RNK];
            #pragma unroll
            for (int k = 0; k < RNK; ++k) d[k] = sD[g+u][k];
            float dot0 = 0.0f, dot1 = 0.0f;
            #pragma unroll
            for (int k = 0; k < RNK; ++k) {
                dot0 = fmaf(d[k], b0[k], dot0);
                dot1 = fmaf(d[k], b1[k], dot1);
            }
            float r0 = (y[u].x != 0.0f) ? y[u].x - dot0 : 0.0f;
            float r1 = (y[u].y != 0.0f) ? y[u].y - dot1 : 0.0f;
            r0 = fminf(fmaxf(r0, -csg0), csg0);   // psi2 * sigma_new
            r1 = fminf(fmaxf(r1, -csg1), csg1);
            #pragma unroll
            for (int k = 0; k < RNK; ++k) {
                a0[k] = fmaf(d[k], r0, a0[k]);
                a1[k] = fmaf(d[k], r1, a1[k]);
            }
        }
        #pragma unroll
        for (int u = 0; u < 4; ++u) y[u] = yn[u];
    }
    #pragma unroll
    for (int k = 0; k < RNK; ++k) {
        atomicAdd(&rhs[k*q + j0],   a0[k]);
        atomicAdd(&rhs[k*q + j0+1], a1[k]);
    }
}

// solve G delta = rhs via stored Cholesky, beta += mu*delta.
// Zeroes tauacc and rhs for the next sweep; zero_g also resets Gbuf.
__global__ void update_kernel(float* __restrict__ Gbuf, float* __restrict__ rhs,
                              float* __restrict__ Bm, const float* __restrict__ mup,
                              float* __restrict__ tauacc, int q, int zero_g) {
    int j = blockIdx.x * TPB + threadIdx.x;
    if (j >= q) return;
    float L[NG];
    #pragma unroll
    for (int k = 0; k < NG; ++k) L[k] = Gbuf[k*q + j];
    float x[RNK];
    #pragma unroll
    for (int k = 0; k < RNK; ++k) x[k] = rhs[k*q + j];
    #pragma unroll
    for (int a = 0; a < RNK; ++a) {          // forward: L y = rhs
        float s = x[a];
        #pragma unroll
        for (int k = 0; k < a; ++k) s -= L[tri(a,k)] * x[k];
        x[a] = s / L[tri(a,a)];
    }
    #pragma unroll
    for (int a = RNK-1; a >= 0; --a) {       // backward: L^T d = y
        float s = x[a];
        #pragma unroll
        for (int k = a+1; k < RNK; ++k) s -= L[tri(k,a)] * x[k];
        x[a] = s / L[tri(a,a)];
    }
    float mu = *mup;
    #pragma unroll
    for (int k = 0; k < RNK; ++k) Bm[k*q + j] += mu * x[k];
    tauacc[j] = 0.0f;
    #pragma unroll
    for (int k = 0; k < RNK; ++k) rhs[k*q + j] = 0.0f;
    if (zero_g) {
        #pragma unroll
        for (int k = 0; k <= NG; ++k) Gbuf[k*q + j] = 0.0f;
    }
}

// final: out[i*n+j] = sum_k Ut[k*m+i] * Vc[k*n+j]
__global__ void gemm_kernel(const float* __restrict__ Ut, const float* __restrict__ Vc,
                            float* __restrict__ out, int m, int n) {
    int j  = blockIdx.x * TPB + threadIdx.x;
    int i0 = blockIdx.y * ITILE;
    float v[RNK];
    #pragma unroll
    for (int k = 0; k < RNK; ++k) v[k] = Vc[k*n + j];
    for (int i = i0; i < i0 + ITILE; ++i) {
        float acc = 0.0f;
        #pragma unroll
        for (int k = 0; k < RNK; ++k) acc = fmaf(Ut[k*m + i], v[k], acc);
        out[(size_t)i*n + j] = acc;
    }
}

// ---------------- host side ----------------

namespace {
struct Scratch {
    float *Ut, *Vc, *Gbuf, *rhs, *sigma, *tauacc, *alpha;
};

static void hubreg(const float* Y, const float* Dm, float* Bm, int q, int p,
                   const float* c, const float* lamda, const float* mu, const float* sigma0,
                   const Scratch& s, hipStream_t stream) {
    dim3 gg(q / TPB, p / ROWS_G);        // gram+pass1(it0)
    dim3 gp(q / (2 * TPB), p / ROWS_P);  // 2-col pass kernels
    dim3 gj(q / TPB);                    // per-regression kernels

    gp1_kernel   <<<gg, TPB, 0, stream>>>(Y, Dm, Bm, c, sigma0, s.Gbuf, s.tauacc, q, p);
    chol_kernel  <<<gj, TPB, 0, stream>>>(s.Gbuf, s.rhs, q);
    pass2_kernel <<<gp, TPB, 0, stream>>>(Y, Dm, Bm, s.Gbuf, s.tauacc, s.sigma, c,
                                          s.alpha, lamda, sigma0, s.rhs, q, p, 0);
    update_kernel<<<gj, TPB, 0, stream>>>(s.Gbuf, s.rhs, Bm, mu, s.tauacc, q, 0);
    pass1_kernel <<<gp, TPB, 0, stream>>>(Y, Dm, Bm, s.sigma, c, s.tauacc, q, p);
    pass2_kernel <<<gp, TPB, 0, stream>>>(Y, Dm, Bm, s.Gbuf, s.tauacc, s.sigma, c,
                                          s.alpha, lamda, sigma0, s.rhs, q, p, 1);
    update_kernel<<<gj, TPB, 0, stream>>>(s.Gbuf, s.rhs, Bm, mu, s.tauacc, q, 1);
}
} // namespace

extern "C" void kernel_launch(void* const* d_in, const int* in_sizes, int n_in,
                              void* d_out, int out_size, void* d_ws, size_t ws_size,
                              hipStream_t stream) {
    const float* Uin    = (const float*)d_in[0];
    const float* Vin    = (const float*)d_in[1];
    const float* X      = (const float*)d_in[2];
    const float* c      = (const float*)d_in[3];
    const float* lamda  = (const float*)d_in[4];
    const float* mu     = (const float*)d_in[5];
    const float* sigma0 = (const float*)d_in[6];
    float* out = (float*)d_out;

    const int m = in_sizes[0] / RNK;   // 4096
    const int n = in_sizes[1] / RNK;   // 4096
    const int qmax = (m > n) ? m : n;

    float* w = (float*)d_ws;
    auto align64 = [](size_t x) { return (x + 63) & ~(size_t)63; };
    size_t off = 0;
    Scratch s;
    s.Ut     = w + off; off = align64(off + (size_t)RNK * m);
    s.Vc     = w + off; off = align64(off + (size_t)RNK * n);
    s.Gbuf   = w + off; off = align64(off + (size_t)(NG + 1) * qmax);
    s.rhs    = w + off; off = align64(off + (size_t)RNK * qmax);
    s.sigma  = w + off; off = align64(off + (size_t)qmax);
    s.tauacc = w + off; off = align64(off + (size_t)qmax);
    s.alpha  = w + off; off = align64(off + 64);
    (void)ws_size; (void)n_in; (void)out_size;

    {
        int tot = (NG + 1) * qmax;
        init_kernel<<<(tot + TPB - 1) / TPB, TPB, 0, stream>>>(
            Uin, Vin, c, s.Ut, s.Vc, s.Gbuf, s.tauacc, s.alpha, m, n, qmax);
    }
    // X [m,n] -> XT [n,m] staged in d_out (dead until final GEMM overwrites it)
    transpose_kernel<<<dim3(n / 32, m / 32), dim3(32, 8), 0, stream>>>(X, out, m, n);

    for (int layer = 0; layer < 3; ++layer) {
        // V-step: q=n regressions (columns of X), D = U rows, beta = V cols
        hubreg(X,   s.Ut, s.Vc, n, m, c, lamda, mu, sigma0, s, stream);
        // U-step: q=m regressions (rows of X), Y = XT, D = V cols, beta = U rows
        hubreg(out, s.Vc, s.Ut, m, n, c, lamda, mu, sigma0, s, stream);
    }

    gemm_kernel<<<dim3(n / TPB, m / ITILE), TPB, 0, stream>>>(s.Ut, s.Vc, out, m, n);
}

// Round 5
// 1570.302 us; speedup vs baseline: 1.0066x; 1.0066x over previous
//
#include <hip/hip_runtime.h>
#include <math.h>

#define RNK 10
#define NG  55          // packed lower-triangular 10x10
#define TPB 256
#define ROWS_G 64       // rows per chunk, fused gram+pass1
#define ROWS_P 32       // rows per chunk, pass1/pass2
#define ITILE 16        // rows per block in final GEMM

__device__ __forceinline__ constexpr int tri(int a, int b) { return a*(a+1)/2 + b; }

// ---------------- init ----------------
__global__ void init_kernel(const float* __restrict__ Uin, const float* __restrict__ Vin,
                            const float* __restrict__ cptr,
                            float* __restrict__ Ut, float* __restrict__ Vc,
                            float* __restrict__ Gbuf, float* __restrict__ tauacc,
                            float* __restrict__ alpha, int m, int n, int qmax) {
    int idx = blockIdx.x * TPB + threadIdx.x;
    if (idx == 0) {
        float c  = *cptr;
        float A  = erff(c * 0.70710678118654752f);              // chi2_cdf(c^2, 1)
        float B  = c * 0.79788456080286536f * expf(-0.5f*c*c);
        *alpha = 0.5f*c*c*(1.0f - A) + 0.5f*(A - B);            // chi2_cdf(c^2,3)=A-B
    }
    if (idx < RNK * m) { int k = idx / m, i = idx - k*m; Ut[idx] = Uin[i*RNK + k]; }
    if (idx < RNK * n) Vc[idx] = Vin[idx];
    if (idx < (NG + 1) * qmax) Gbuf[idx] = 0.0f;
    if (idx < qmax) tauacc[idx] = 0.0f;
}

// X [m,n] -> XT [n,m], 32x32 LDS tile
__global__ void transpose_kernel(const float* __restrict__ X, float* __restrict__ XT,
                                 int m, int n) {
    __shared__ float tile[32][33];
    int bx = blockIdx.x * 32, by = blockIdx.y * 32;
    int tx = threadIdx.x, ty = threadIdx.y;  // block (32,8)
    #pragma unroll
    for (int dy = 0; dy < 32; dy += 8)
        tile[ty+dy][tx] = X[(size_t)(by+ty+dy)*n + bx + tx];
    __syncthreads();
    #pragma unroll
    for (int dy = 0; dy < 32; dy += 8)
        XT[(size_t)(bx+ty+dy)*m + by + tx] = tile[tx][ty+dy];
}

// ---------------- hubreg kernels ----------------
// Layouts: Y [p,q] (regression j fast axis), Dm [r,p] (wave-uniform rows ->
// compiler emits SMEM s_load broadcasts; do NOT stage in LDS), Bm [r,q].
// amdgpu_waves_per_eu(4,4): cap AND target 4 waves/EU -> allocator free to use
// up to 128 VGPRs (round 3/4 squeezed to 64 and spilled the Gram accumulators).

// Fused Gram + pass1(it=0), 8-deep Y prefetch.
__global__ __launch_bounds__(TPB)
__attribute__((amdgpu_waves_per_eu(4, 4)))
void gp1_kernel(const float* __restrict__ Y, const float* __restrict__ Dm,
                const float* __restrict__ Bm, const float* __restrict__ cptr,
                const float* __restrict__ sigma0,
                float* __restrict__ Gbuf, float* __restrict__ tauacc,
                int q, int p) {
    int j  = blockIdx.x * TPB + threadIdx.x;
    int i0 = blockIdx.y * ROWS_G;
    float b[RNK];
    #pragma unroll
    for (int k = 0; k < RNK; ++k) b[k] = Bm[k*q + j];
    float csg = (*cptr) * (*sigma0);
    float acc[NG];
    #pragma unroll
    for (int k = 0; k < NG; ++k) acc[k] = 0.0f;
    float cnt = 0.0f, p1 = 0.0f;
    float y[8];
    #pragma unroll
    for (int u = 0; u < 8; ++u) y[u] = Y[(size_t)(i0+u)*q + j];
    for (int g = 0; g < ROWS_G; g += 8) {
        float yn[8];
        if (g + 8 < ROWS_G) {
            #pragma unroll
            for (int u = 0; u < 8; ++u) yn[u] = Y[(size_t)(i0+g+8+u)*q + j];
        } else {
            #pragma unroll
            for (int u = 0; u < 8; ++u) yn[u] = 0.0f;
        }
        #pragma unroll
        for (int u = 0; u < 8; ++u) {
            int i = i0 + g + u;
            float d[RNK];
            #pragma unroll
            for (int k = 0; k < RNK; ++k) d[k] = Dm[k*p + i];
            float yv  = y[u];
            float msk = (yv != 0.0f) ? 1.0f : 0.0f;
            cnt += msk;
            float dot = 0.0f;
            #pragma unroll
            for (int k = 0; k < RNK; ++k) dot = fmaf(d[k], b[k], dot);
            float r = (yv != 0.0f) ? yv - dot : 0.0f;
            r = fminf(fmaxf(r, -csg), csg);          // psi(R/sig0)*sig0
            p1 = fmaf(r, r, p1);
            float dm[RNK];
            #pragma unroll
            for (int k = 0; k < RNK; ++k) dm[k] = msk * d[k];
            #pragma unroll
            for (int a = 0; a < RNK; ++a)
                #pragma unroll
                for (int bb = 0; bb <= a; ++bb)
                    acc[tri(a,bb)] = fmaf(dm[a], d[bb], acc[tri(a,bb)]);
        }
        #pragma unroll
        for (int u = 0; u < 8; ++u) y[u] = yn[u];
    }
    #pragma unroll
    for (int k = 0; k < NG; ++k) atomicAdd(&Gbuf[k*q + j], acc[k]);
    atomicAdd(&Gbuf[NG*q + j], cnt);
    atomicAdd(&tauacc[j], p1);
}

// Cholesky (packed, in registers) + zero rhs for the following pass2
__global__ void chol_kernel(float* __restrict__ Gbuf, float* __restrict__ rhs, int q) {
    int j = blockIdx.x * TPB + threadIdx.x;
    if (j >= q) return;
    float g[NG];
    #pragma unroll
    for (int k = 0; k < NG; ++k) g[k] = Gbuf[k*q + j];
    #pragma unroll
    for (int a = 0; a < RNK; ++a) {
        #pragma unroll
        for (int b = 0; b < a; ++b) {
            float s = g[tri(a,b)];
            #pragma unroll
            for (int k = 0; k < b; ++k) s -= g[tri(a,k)] * g[tri(b,k)];
            g[tri(a,b)] = s / g[tri(b,b)];
        }
        float s = g[tri(a,a)];
        #pragma unroll
        for (int k = 0; k < a; ++k) s -= g[tri(a,k)] * g[tri(a,k)];
        g[tri(a,a)] = sqrtf(s);
    }
    #pragma unroll
    for (int k = 0; k < NG; ++k) Gbuf[k*q + j] = g[k];
    #pragma unroll
    for (int k = 0; k < RNK; ++k) rhs[k*q + j] = 0.0f;
}

// pass1 (it=1): sum of (psi*sigma1)^2; sigma1 was stored by pass2(it=0).
// 2 cols x 8-deep float2 prefetch.
__global__ __launch_bounds__(TPB)
__attribute__((amdgpu_waves_per_eu(4, 4)))
void pass1_kernel(const float* __restrict__ Y, const float* __restrict__ Dm,
                  const float* __restrict__ Bm, const float* __restrict__ sigstore,
                  const float* __restrict__ cptr, float* __restrict__ tauacc,
                  int q, int p) {
    int j0 = 2 * (blockIdx.x * TPB + threadIdx.x);
    int i0 = blockIdx.y * ROWS_P;
    float b0[RNK], b1[RNK];
    #pragma unroll
    for (int k = 0; k < RNK; ++k) {
        float2 bv = *(const float2*)&Bm[k*q + j0];
        b0[k] = bv.x; b1[k] = bv.y;
    }
    float c = *cptr;
    float csg0 = c * sigstore[j0], csg1 = c * sigstore[j0+1];
    float a0 = 0.0f, a1 = 0.0f;
    float2 y[8];
    #pragma unroll
    for (int u = 0; u < 8; ++u) y[u] = *(const float2*)&Y[(size_t)(i0+u)*q + j0];
    for (int g = 0; g < ROWS_P; g += 8) {
        float2 yn[8];
        if (g + 8 < ROWS_P) {
            #pragma unroll
            for (int u = 0; u < 8; ++u) yn[u] = *(const float2*)&Y[(size_t)(i0+g+8+u)*q + j0];
        } else {
            #pragma unroll
            for (int u = 0; u < 8; ++u) yn[u] = make_float2(0.0f, 0.0f);
        }
        #pragma unroll
        for (int u = 0; u < 8; ++u) {
            int i = i0 + g + u;
            float dot0 = 0.0f, dot1 = 0.0f;
            #pragma unroll
            for (int k = 0; k < RNK; ++k) {
                float d = Dm[k*p + i];
                dot0 = fmaf(d, b0[k], dot0);
                dot1 = fmaf(d, b1[k], dot1);
            }
            float r0 = (y[u].x != 0.0f) ? y[u].x - dot0 : 0.0f;
            float r1 = (y[u].y != 0.0f) ? y[u].y - dot1 : 0.0f;
            r0 = fminf(fmaxf(r0, -csg0), csg0);
            r1 = fminf(fmaxf(r1, -csg1), csg1);
            a0 = fmaf(r0, r0, a0);
            a1 = fmaf(r1, r1, a1);
        }
        #pragma unroll
        for (int u = 0; u < 8; ++u) y[u] = yn[u];
    }
    atomicAdd(&tauacc[j0],   a0);
    atomicAdd(&tauacc[j0+1], a1);
}

// pass2: sigma_new computed inline from tauacc; rhs += D^T psi2*sigma_new.
// mode 0 (it=0): sig_old = *sigma0, chunk-0 stores sigma_new for pass1(it=1).
// mode 1 (it=1): sig_old = sigstore[j].
__global__ __launch_bounds__(TPB)
__attribute__((amdgpu_waves_per_eu(4, 4)))
void pass2_kernel(const float* __restrict__ Y, const float* __restrict__ Dm,
                  const float* __restrict__ Bm, const float* __restrict__ Gbuf,
                  const float* __restrict__ tauacc, float* __restrict__ sigstore,
                  const float* __restrict__ cptr, const float* __restrict__ alphap,
                  const float* __restrict__ lamdap, const float* __restrict__ sigma0p,
                  float* __restrict__ rhs, int q, int p, int mode) {
    int j0 = 2 * (blockIdx.x * TPB + threadIdx.x);
    int i0 = blockIdx.y * ROWS_P;
    float b0[RNK], b1[RNK];
    #pragma unroll
    for (int k = 0; k < RNK; ++k) {
        float2 bv = *(const float2*)&Bm[k*q + j0];
        b0[k] = bv.x; b1[k] = bv.y;
    }
    float c = *cptr, alpha = *alphap, lam = *lamdap;
    float so0 = mode ? sigstore[j0]   : *sigma0p;
    float so1 = mode ? sigstore[j0+1] : *sigma0p;
    float nb0 = Gbuf[NG*q + j0], nb1 = Gbuf[NG*q + j0+1];
    float t0 = sqrtf(tauacc[j0]   / (2.0f * nb0 * alpha)) / so0;
    float t1 = sqrtf(tauacc[j0+1] / (2.0f * nb1 * alpha)) / so1;
    float sg0 = so0 * powf(t0, lam);
    float sg1 = so1 * powf(t1, lam);
    if (mode == 0 && blockIdx.y == 0) { sigstore[j0] = sg0; sigstore[j0+1] = sg1; }
    float csg0 = c * sg0, csg1 = c * sg1;

    float a0[RNK], a1[RNK];
    #pragma unroll
    for (int k = 0; k < RNK; ++k) { a0[k] = 0.0f; a1[k] = 0.0f; }
    float2 y[8];
    #pragma unroll
    for (int u = 0; u < 8; ++u) y[u] = *(const float2*)&Y[(size_t)(i0+u)*q + j0];
    for (int g = 0; g < ROWS_P; g += 8) {
        float2 yn[8];
        if (g + 8 < ROWS_P) {
            #pragma unroll
            for (int u = 0; u < 8; ++u) yn[u] = *(const float2*)&Y[(size_t)(i0+g+8+u)*q + j0];
        } else {
            #pragma unroll
            for (int u = 0; u < 8; ++u) yn[u] = make_float2(0.0f, 0.0f);
        }
        #pragma unroll
        for (int u = 0; u < 8; ++u) {
            int i = i0 + g + u;
            float d[RNK];
            #pragma unroll
            for (int k = 0; k < RNK; ++k) d[k] = Dm[k*p + i];
            float dot0 = 0.0f, dot1 = 0.0f;
            #pragma unroll
            for (int k = 0; k < RNK; ++k) {
                dot0 = fmaf(d[k], b0[k], dot0);
                dot1 = fmaf(d[k], b1[k], dot1);
            }
            float r0 = (y[u].x != 0.0f) ? y[u].x - dot0 : 0.0f;
            float r1 = (y[u].y != 0.0f) ? y[u].y - dot1 : 0.0f;
            r0 = fminf(fmaxf(r0, -csg0), csg0);   // psi2 * sigma_new
            r1 = fminf(fmaxf(r1, -csg1), csg1);
            #pragma unroll
            for (int k = 0; k < RNK; ++k) {
                a0[k] = fmaf(d[k], r0, a0[k]);
                a1[k] = fmaf(d[k], r1, a1[k]);
            }
        }
        #pragma unroll
        for (int u = 0; u < 8; ++u) y[u] = yn[u];
    }
    #pragma unroll
    for (int k = 0; k < RNK; ++k) {
        atomicAdd(&rhs[k*q + j0],   a0[k]);
        atomicAdd(&rhs[k*q + j0+1], a1[k]);
    }
}

// solve G delta = rhs via stored Cholesky, beta += mu*delta.
// Zeroes tauacc and rhs for the next sweep; zero_g also resets Gbuf.
__global__ void update_kernel(float* __restrict__ Gbuf, float* __restrict__ rhs,
                              float* __restrict__ Bm, const float* __restrict__ mup,
                              float* __restrict__ tauacc, int q, int zero_g) {
    int j = blockIdx.x * TPB + threadIdx.x;
    if (j >= q) return;
    float L[NG];
    #pragma unroll
    for (int k = 0; k < NG; ++k) L[k] = Gbuf[k*q + j];
    float x[RNK];
    #pragma unroll
    for (int k = 0; k < RNK; ++k) x[k] = rhs[k*q + j];
    #pragma unroll
    for (int a = 0; a < RNK; ++a) {          // forward: L y = rhs
        float s = x[a];
        #pragma unroll
        for (int k = 0; k < a; ++k) s -= L[tri(a,k)] * x[k];
        x[a] = s / L[tri(a,a)];
    }
    #pragma unroll
    for (int a = RNK-1; a >= 0; --a) {       // backward: L^T d = y
        float s = x[a];
        #pragma unroll
        for (int k = a+1; k < RNK; ++k) s -= L[tri(k,a)] * x[k];
        x[a] = s / L[tri(a,a)];
    }
    float mu = *mup;
    #pragma unroll
    for (int k = 0; k < RNK; ++k) Bm[k*q + j] += mu * x[k];
    tauacc[j] = 0.0f;
    #pragma unroll
    for (int k = 0; k < RNK; ++k) rhs[k*q + j] = 0.0f;
    if (zero_g) {
        #pragma unroll
        for (int k = 0; k <= NG; ++k) Gbuf[k*q + j] = 0.0f;
    }
}

// final: out[i*n+j] = sum_k Ut[k*m+i] * Vc[k*n+j]
__global__ void gemm_kernel(const float* __restrict__ Ut, const float* __restrict__ Vc,
                            float* __restrict__ out, int m, int n) {
    int j  = blockIdx.x * TPB + threadIdx.x;
    int i0 = blockIdx.y * ITILE;
    float v[RNK];
    #pragma unroll
    for (int k = 0; k < RNK; ++k) v[k] = Vc[k*n + j];
    for (int i = i0; i < i0 + ITILE; ++i) {
        float acc = 0.0f;
        #pragma unroll
        for (int k = 0; k < RNK; ++k) acc = fmaf(Ut[k*m + i], v[k], acc);
        out[(size_t)i*n + j] = acc;
    }
}

// ---------------- host side ----------------

namespace {
struct Scratch {
    float *Ut, *Vc, *Gbuf, *rhs, *sigma, *tauacc, *alpha;
};

static void hubreg(const float* Y, const float* Dm, float* Bm, int q, int p,
                   const float* c, const float* lamda, const float* mu, const float* sigma0,
                   const Scratch& s, hipStream_t stream) {
    dim3 gg(q / TPB, p / ROWS_G);        // gram+pass1(it0)
    dim3 gp(q / (2 * TPB), p / ROWS_P);  // 2-col pass kernels
    dim3 gj(q / TPB);                    // per-regression kernels

    gp1_kernel   <<<gg, TPB, 0, stream>>>(Y, Dm, Bm, c, sigma0, s.Gbuf, s.tauacc, q, p);
    chol_kernel  <<<gj, TPB, 0, stream>>>(s.Gbuf, s.rhs, q);
    pass2_kernel <<<gp, TPB, 0, stream>>>(Y, Dm, Bm, s.Gbuf, s.tauacc, s.sigma, c,
                                          s.alpha, lamda, sigma0, s.rhs, q, p, 0);
    update_kernel<<<gj, TPB, 0, stream>>>(s.Gbuf, s.rhs, Bm, mu, s.tauacc, q, 0);
    pass1_kernel <<<gp, TPB, 0, stream>>>(Y, Dm, Bm, s.sigma, c, s.tauacc, q, p);
    pass2_kernel <<<gp, TPB, 0, stream>>>(Y, Dm, Bm, s.Gbuf, s.tauacc, s.sigma, c,
                                          s.alpha, lamda, sigma0, s.rhs, q, p, 1);
    update_kernel<<<gj, TPB, 0, stream>>>(s.Gbuf, s.rhs, Bm, mu, s.tauacc, q, 1);
}
} // namespace

extern "C" void kernel_launch(void* const* d_in, const int* in_sizes, int n_in,
                              void* d_out, int out_size, void* d_ws, size_t ws_size,
                              hipStream_t stream) {
    const float* Uin    = (const float*)d_in[0];
    const float* Vin    = (const float*)d_in[1];
    const float* X      = (const float*)d_in[2];
    const float* c      = (const float*)d_in[3];
    const float* lamda  = (const float*)d_in[4];
    const float* mu     = (const float*)d_in[5];
    const float* sigma0 = (const float*)d_in[6];
    float* out = (float*)d_out;

    const int m = in_sizes[0] / RNK;   // 4096
    const int n = in_sizes[1] / RNK;   // 4096
    const int qmax = (m > n) ? m : n;

    float* w = (float*)d_ws;
    auto align64 = [](size_t x) { return (x + 63) & ~(size_t)63; };
    size_t off = 0;
    Scratch s;
    s.Ut     = w + off; off = align64(off + (size_t)RNK * m);
    s.Vc     = w + off; off = align64(off + (size_t)RNK * n);
    s.Gbuf   = w + off; off = align64(off + (size_t)(NG + 1) * qmax);
    s.rhs    = w + off; off = align64(off + (size_t)RNK * qmax);
    s.sigma  = w + off; off = align64(off + (size_t)qmax);
    s.tauacc = w + off; off = align64(off + (size_t)qmax);
    s.alpha  = w + off; off = align64(off + 64);
    (void)ws_size; (void)n_in; (void)out_size;

    {
        int tot = (NG + 1) * qmax;
        init_kernel<<<(tot + TPB - 1) / TPB, TPB, 0, stream>>>(
            Uin, Vin, c, s.Ut, s.Vc, s.Gbuf, s.tauacc, s.alpha, m, n, qmax);
    }
    // X [m,n] -> XT [n,m] staged in d_out (dead until final GEMM overwrites it)
    transpose_kernel<<<dim3(n / 32, m / 32), dim3(32, 8), 0, stream>>>(X, out, m, n);

    for (int layer = 0; layer < 3; ++layer) {
        // V-step: q=n regressions (columns of X), D = U rows, beta = V cols
        hubreg(X,   s.Ut, s.Vc, n, m, c, lamda, mu, sigma0, s, stream);
        // U-step: q=m regressions (rows of X), Y = XT, D = V cols, beta = U rows
        hubreg(out, s.Vc, s.Ut, m, n, c, lamda, mu, sigma0, s, stream);
    }

    gemm_kernel<<<dim3(n / TPB, m / ITILE), TPB, 0, stream>>>(s.Ut, s.Vc, out, m, n);
}

// Round 6
// 1182.294 us; speedup vs baseline: 1.3370x; 1.3282x over previous
//
#include <hip/hip_runtime.h>
#include <math.h>

#define RNK 10
#define NG  55          // packed lower-triangular 10x10
#define TPB 256
#define WPC 4           // mask words (32 rows each) per gram chunk -> 128 rows
#define ROWS_P 32       // rows per chunk, pass1/pass2
#define ITILE 16        // rows per block in final GEMM

__device__ __forceinline__ constexpr int tri(int a, int b) { return a*(a+1)/2 + b; }

// ---------------- init ----------------
// Ut[r,m]<-U^T, Urow[m,10]<-U, Vc[r,n]<-V, Vrow[n,10]<-V^T, zero Gbuf/tauacc/rhs, alpha
__global__ void init_kernel(const float* __restrict__ Uin, const float* __restrict__ Vin,
                            const float* __restrict__ cptr,
                            float* __restrict__ Ut, float* __restrict__ Vc,
                            float* __restrict__ Urow, float* __restrict__ Vrow,
                            float* __restrict__ Gbuf, float* __restrict__ tauacc,
                            float* __restrict__ rhs, float* __restrict__ alpha,
                            int m, int n, int qmax) {
    int idx = blockIdx.x * TPB + threadIdx.x;
    if (idx == 0) {
        float c  = *cptr;
        float A  = erff(c * 0.70710678118654752f);              // chi2_cdf(c^2, 1)
        float B  = c * 0.79788456080286536f * expf(-0.5f*c*c);
        *alpha = 0.5f*c*c*(1.0f - A) + 0.5f*(A - B);            // chi2_cdf(c^2,3)=A-B
    }
    if (idx < RNK * m) { int k = idx / m, i = idx - k*m; Ut[idx] = Uin[i*RNK + k]; }
    if (idx < RNK * m) Urow[idx] = Uin[idx];                    // same layout
    if (idx < RNK * n) Vc[idx] = Vin[idx];
    if (idx < RNK * n) { int j = idx / RNK, k = idx - j*RNK; Vrow[idx] = Vin[k*n + j]; }
    if (idx < (NG + 1) * qmax) Gbuf[idx] = 0.0f;
    if (idx < qmax) tauacc[idx] = 0.0f;
    if (idx < RNK * qmax) rhs[idx] = 0.0f;
}

// X [m,n] -> XT [n,m], 32x32 LDS tile
__global__ void transpose_kernel(const float* __restrict__ X, float* __restrict__ XT,
                                 int m, int n) {
    __shared__ float tile[32][33];
    int bx = blockIdx.x * 32, by = blockIdx.y * 32;
    int tx = threadIdx.x, ty = threadIdx.y;  // block (32,8)
    #pragma unroll
    for (int dy = 0; dy < 32; dy += 8)
        tile[ty+dy][tx] = X[(size_t)(by+ty+dy)*n + bx + tx];
    __syncthreads();
    #pragma unroll
    for (int dy = 0; dy < 32; dy += 8)
        XT[(size_t)(bx+ty+dy)*m + by + tx] = tile[tx][ty+dy];
}

// Build packed masks. maskV [m/32][n]: bit u of word (w,j) = (X[32w+u, j] != 0).
// maskU [n/32][m]: bit u of word (w,i) = (X[i, 32w+u] != 0)  (via 64-lane ballot).
// grid (n/256, m/32), block 256 = 4 waves; each wave: 64 cols x 32 rows.
__global__ void mask_kernel(const float* __restrict__ X, unsigned* __restrict__ maskV,
                            unsigned* __restrict__ maskU, int m, int n) {
    int wave = threadIdx.x >> 6, lane = threadIdx.x & 63;
    int jbase = blockIdx.x * 256 + wave * 64;
    int j  = jbase + lane;
    int i0 = blockIdx.y * 32;
    unsigned wv = 0;
    for (int u = 0; u < 32; ++u) {
        float x = X[(size_t)(i0+u)*n + j];
        bool nz = (x != 0.0f);
        wv |= (nz ? 1u : 0u) << u;
        unsigned long long bb = __ballot(nz);
        if (lane == 0) {
            int jw = jbase >> 5;
            maskU[(size_t)jw     * m + (i0+u)] = (unsigned)bb;
            maskU[(size_t)(jw+1) * m + (i0+u)] = (unsigned)(bb >> 32);
        }
    }
    maskV[(size_t)blockIdx.y * n + j] = wv;
}

// ---------------- hubreg kernels ----------------
// Gram from packed mask bits only: no Y stream. D rows via wave-uniform s_load
// (Drow row-major) -> SGPRs. Per-lane VGPRs ~= 55 acc + 4 words + misc: fits 64.
// f in {0,1}: acc[a][b] += (f*d[a]) * d[b]; nobs via popcount.
__global__ __launch_bounds__(TPB)
void gram_kernel(const unsigned* __restrict__ mask, const float* __restrict__ Drow,
                 float* __restrict__ Gbuf, int q, int p) {
    int j  = blockIdx.x * TPB + threadIdx.x;
    int w0 = blockIdx.y * WPC;
    unsigned words[WPC];
    #pragma unroll
    for (int w = 0; w < WPC; ++w) words[w] = mask[(size_t)(w0+w)*q + j];
    float acc[NG];
    #pragma unroll
    for (int k = 0; k < NG; ++k) acc[k] = 0.0f;
    unsigned cnt = 0;
    int ib = w0 * 32;
    // prefetch first D row (wave-uniform -> SGPRs)
    float dc[RNK];
    #pragma unroll
    for (int k = 0; k < RNK; ++k) dc[k] = Drow[(size_t)ib*RNK + k];
    #pragma unroll
    for (int w = 0; w < WPC; ++w) {
        unsigned word = words[w];
        cnt += __popc(word);
        for (int u = 0; u < 32; ++u) {
            int inext = ib + w*32 + u + 1;
            if (inext > p - 1) inext = p - 1;
            float dn[RNK];
            #pragma unroll
            for (int k = 0; k < RNK; ++k) dn[k] = Drow[(size_t)inext*RNK + k];
            float f = (float)((word >> u) & 1u);
            #pragma unroll
            for (int a = 0; a < RNK; ++a) {
                float t = f * dc[a];
                #pragma unroll
                for (int b = 0; b <= a; ++b)
                    acc[tri(a,b)] = fmaf(t, dc[b], acc[tri(a,b)]);
            }
            #pragma unroll
            for (int k = 0; k < RNK; ++k) dc[k] = dn[k];
        }
    }
    #pragma unroll
    for (int k = 0; k < NG; ++k) atomicAdd(&Gbuf[k*q + j], acc[k]);
    atomicAdd(&Gbuf[NG*q + j], (float)cnt);
}

// pass1: tauacc[j] += sum_i (clamp(resid, +-c*sig))^2. 1 col/thread, 8-deep prefetch.
// use_store=0: sig = *sigma0p (it=0);  use_store=1: sig = sigstore[j] (it=1).
__global__ __launch_bounds__(TPB)
void pass1_kernel(const float* __restrict__ Y, const float* __restrict__ Drow,
                  const float* __restrict__ Bm, const float* __restrict__ sigstore,
                  const float* __restrict__ sigma0p, const float* __restrict__ cptr,
                  float* __restrict__ tauacc, int q, int p, int use_store) {
    int j  = blockIdx.x * TPB + threadIdx.x;
    int i0 = blockIdx.y * ROWS_P;
    float b[RNK];
    #pragma unroll
    for (int k = 0; k < RNK; ++k) b[k] = Bm[k*q + j];
    float csg = (*cptr) * (use_store ? sigstore[j] : *sigma0p);
    float a0 = 0.0f;
    float y[8];
    #pragma unroll
    for (int u = 0; u < 8; ++u) y[u] = Y[(size_t)(i0+u)*q + j];
    for (int g = 0; g < ROWS_P; g += 8) {
        float yn[8];
        if (g + 8 < ROWS_P) {
            #pragma unroll
            for (int u = 0; u < 8; ++u) yn[u] = Y[(size_t)(i0+g+8+u)*q + j];
        } else {
            #pragma unroll
            for (int u = 0; u < 8; ++u) yn[u] = 0.0f;
        }
        #pragma unroll
        for (int u = 0; u < 8; ++u) {
            int i = i0 + g + u;
            const float* dd = Drow + (size_t)i*RNK;   // wave-uniform -> s_load
            float dot = 0.0f;
            #pragma unroll
            for (int k = 0; k < RNK; ++k) dot = fmaf(dd[k], b[k], dot);
            float r = (y[u] != 0.0f) ? y[u] - dot : 0.0f;
            r = fminf(fmaxf(r, -csg), csg);
            a0 = fmaf(r, r, a0);
        }
        #pragma unroll
        for (int u = 0; u < 8; ++u) y[u] = yn[u];
    }
    atomicAdd(&tauacc[j], a0);
}

// pass2: sigma_new inline from tauacc; rhs[k][j] += D[i,k]*clamp(resid,+-c*sigma_new).
// mode 0: sig_old = *sigma0p, chunk-0 stores sigma_new. mode 1: sig_old = sigstore[j].
__global__ __launch_bounds__(TPB)
void pass2_kernel(const float* __restrict__ Y, const float* __restrict__ Drow,
                  const float* __restrict__ Bm, const float* __restrict__ Gbuf,
                  const float* __restrict__ tauacc, float* __restrict__ sigstore,
                  const float* __restrict__ cptr, const float* __restrict__ alphap,
                  const float* __restrict__ lamdap, const float* __restrict__ sigma0p,
                  float* __restrict__ rhs, int q, int p, int mode) {
    int j  = blockIdx.x * TPB + threadIdx.x;
    int i0 = blockIdx.y * ROWS_P;
    float b[RNK];
    #pragma unroll
    for (int k = 0; k < RNK; ++k) b[k] = Bm[k*q + j];
    float so  = mode ? sigstore[j] : *sigma0p;
    float nb  = Gbuf[NG*q + j];
    float tau = sqrtf(tauacc[j] / (2.0f * nb * (*alphap))) / so;
    float sg  = so * powf(tau, *lamdap);
    if (mode == 0 && blockIdx.y == 0) sigstore[j] = sg;
    float csg = (*cptr) * sg;

    float a[RNK];
    #pragma unroll
    for (int k = 0; k < RNK; ++k) a[k] = 0.0f;
    float y[8];
    #pragma unroll
    for (int u = 0; u < 8; ++u) y[u] = Y[(size_t)(i0+u)*q + j];
    for (int g = 0; g < ROWS_P; g += 8) {
        float yn[8];
        if (g + 8 < ROWS_P) {
            #pragma unroll
            for (int u = 0; u < 8; ++u) yn[u] = Y[(size_t)(i0+g+8+u)*q + j];
        } else {
            #pragma unroll
            for (int u = 0; u < 8; ++u) yn[u] = 0.0f;
        }
        #pragma unroll
        for (int u = 0; u < 8; ++u) {
            int i = i0 + g + u;
            const float* dd = Drow + (size_t)i*RNK;   // wave-uniform -> s_load
            float dot = 0.0f;
            #pragma unroll
            for (int k = 0; k < RNK; ++k) dot = fmaf(dd[k], b[k], dot);
            float r = (y[u] != 0.0f) ? y[u] - dot : 0.0f;
            r = fminf(fmaxf(r, -csg), csg);   // psi2 * sigma_new
            #pragma unroll
            for (int k = 0; k < RNK; ++k) a[k] = fmaf(dd[k], r, a[k]);
        }
        #pragma unroll
        for (int u = 0; u < 8; ++u) y[u] = yn[u];
    }
    #pragma unroll
    for (int k = 0; k < RNK; ++k) atomicAdd(&rhs[k*q + j], a[k]);
}

// Cholesky of raw G (in registers) + solve + beta += mu*delta.
// Writes BOTH beta layouts (Bm [r,q] and Brow [q,r]). Zeroes tauacc and rhs;
// zero_g also resets Gbuf for the next hubreg call.
__global__ void update_kernel(float* __restrict__ Gbuf, float* __restrict__ rhs,
                              float* __restrict__ Bm, float* __restrict__ Brow,
                              const float* __restrict__ mup,
                              float* __restrict__ tauacc, int q, int zero_g) {
    int j = blockIdx.x * TPB + threadIdx.x;
    if (j >= q) return;
    float g[NG];
    #pragma unroll
    for (int k = 0; k < NG; ++k) g[k] = Gbuf[k*q + j];
    #pragma unroll
    for (int a = 0; a < RNK; ++a) {          // in-register Cholesky
        #pragma unroll
        for (int b = 0; b < a; ++b) {
            float s = g[tri(a,b)];
            #pragma unroll
            for (int k = 0; k < b; ++k) s -= g[tri(a,k)] * g[tri(b,k)];
            g[tri(a,b)] = s / g[tri(b,b)];
        }
        float s = g[tri(a,a)];
        #pragma unroll
        for (int k = 0; k < a; ++k) s -= g[tri(a,k)] * g[tri(a,k)];
        g[tri(a,a)] = sqrtf(s);
    }
    float x[RNK];
    #pragma unroll
    for (int k = 0; k < RNK; ++k) x[k] = rhs[k*q + j];
    #pragma unroll
    for (int a = 0; a < RNK; ++a) {          // forward: L y = rhs
        float s = x[a];
        #pragma unroll
        for (int k = 0; k < a; ++k) s -= g[tri(a,k)] * x[k];
        x[a] = s / g[tri(a,a)];
    }
    #pragma unroll
    for (int a = RNK-1; a >= 0; --a) {       // backward: L^T d = y
        float s = x[a];
        #pragma unroll
        for (int k = a+1; k < RNK; ++k) s -= g[tri(k,a)] * x[k];
        x[a] = s / g[tri(a,a)];
    }
    float mu = *mup;
    #pragma unroll
    for (int k = 0; k < RNK; ++k) {
        float nb = Bm[k*q + j] + mu * x[k];
        Bm[k*q + j] = nb;
        Brow[(size_t)j*RNK + k] = nb;
    }
    tauacc[j] = 0.0f;
    #pragma unroll
    for (int k = 0; k < RNK; ++k) rhs[k*q + j] = 0.0f;
    if (zero_g) {
        #pragma unroll
        for (int k = 0; k <= NG; ++k) Gbuf[k*q + j] = 0.0f;
    }
}

// final: out[i*n+j] = sum_k Ut[k*m+i] * Vc[k*n+j]
__global__ void gemm_kernel(const float* __restrict__ Ut, const float* __restrict__ Vc,
                            float* __restrict__ out, int m, int n) {
    int j  = blockIdx.x * TPB + threadIdx.x;
    int i0 = blockIdx.y * ITILE;
    float v[RNK];
    #pragma unroll
    for (int k = 0; k < RNK; ++k) v[k] = Vc[k*n + j];
    for (int i = i0; i < i0 + ITILE; ++i) {
        float acc = 0.0f;
        #pragma unroll
        for (int k = 0; k < RNK; ++k) acc = fmaf(Ut[k*m + i], v[k], acc);
        out[(size_t)i*n + j] = acc;
    }
}

// ---------------- host side ----------------

namespace {
struct Scratch {
    float *Ut, *Vc, *Urow, *Vrow, *Gbuf, *rhs, *sigma, *tauacc, *alpha;
    unsigned *maskV, *maskU;
};

static void hubreg(const float* Y, const unsigned* mask, const float* Drow,
                   float* Bm, float* Brow, int q, int p,
                   const float* c, const float* lamda, const float* mu, const float* sigma0,
                   const Scratch& s, hipStream_t stream) {
    dim3 gg(q / TPB, p / (32 * WPC));    // gram
    dim3 gp(q / TPB, p / ROWS_P);        // pass kernels (1 col/thread)
    dim3 gj(q / TPB);                    // per-regression kernels

    gram_kernel  <<<gg, TPB, 0, stream>>>(mask, Drow, s.Gbuf, q, p);
    pass1_kernel <<<gp, TPB, 0, stream>>>(Y, Drow, Bm, s.sigma, sigma0, c, s.tauacc, q, p, 0);
    pass2_kernel <<<gp, TPB, 0, stream>>>(Y, Drow, Bm, s.Gbuf, s.tauacc, s.sigma, c,
                                          s.alpha, lamda, sigma0, s.rhs, q, p, 0);
    update_kernel<<<gj, TPB, 0, stream>>>(s.Gbuf, s.rhs, Bm, Brow, mu, s.tauacc, q, 0);
    pass1_kernel <<<gp, TPB, 0, stream>>>(Y, Drow, Bm, s.sigma, sigma0, c, s.tauacc, q, p, 1);
    pass2_kernel <<<gp, TPB, 0, stream>>>(Y, Drow, Bm, s.Gbuf, s.tauacc, s.sigma, c,
                                          s.alpha, lamda, sigma0, s.rhs, q, p, 1);
    update_kernel<<<gj, TPB, 0, stream>>>(s.Gbuf, s.rhs, Bm, Brow, mu, s.tauacc, q, 1);
}
} // namespace

extern "C" void kernel_launch(void* const* d_in, const int* in_sizes, int n_in,
                              void* d_out, int out_size, void* d_ws, size_t ws_size,
                              hipStream_t stream) {
    const float* Uin    = (const float*)d_in[0];
    const float* Vin    = (const float*)d_in[1];
    const float* X      = (const float*)d_in[2];
    const float* c      = (const float*)d_in[3];
    const float* lamda  = (const float*)d_in[4];
    const float* mu     = (const float*)d_in[5];
    const float* sigma0 = (const float*)d_in[6];
    float* out = (float*)d_out;

    const int m = in_sizes[0] / RNK;   // 4096
    const int n = in_sizes[1] / RNK;   // 4096
    const int qmax = (m > n) ? m : n;

    float* w = (float*)d_ws;
    auto align64 = [](size_t x) { return (x + 63) & ~(size_t)63; };
    size_t off = 0;
    Scratch s;
    s.Ut     = w + off; off = align64(off + (size_t)RNK * m);
    s.Vc     = w + off; off = align64(off + (size_t)RNK * n);
    s.Urow   = w + off; off = align64(off + (size_t)RNK * m);
    s.Vrow   = w + off; off = align64(off + (size_t)RNK * n);
    s.Gbuf   = w + off; off = align64(off + (size_t)(NG + 1) * qmax);
    s.rhs    = w + off; off = align64(off + (size_t)RNK * qmax);
    s.sigma  = w + off; off = align64(off + (size_t)qmax);
    s.tauacc = w + off; off = align64(off + (size_t)qmax);
    s.alpha  = w + off; off = align64(off + 64);
    s.maskV  = (unsigned*)(w + off); off = align64(off + (size_t)(m/32) * n);
    s.maskU  = (unsigned*)(w + off); off = align64(off + (size_t)(n/32) * m);
    (void)ws_size; (void)n_in; (void)out_size;

    {
        int tot = (NG + 1) * qmax;
        init_kernel<<<(tot + TPB - 1) / TPB, TPB, 0, stream>>>(
            Uin, Vin, c, s.Ut, s.Vc, s.Urow, s.Vrow, s.Gbuf, s.tauacc, s.rhs,
            s.alpha, m, n, qmax);
    }
    // X [m,n] -> XT [n,m] staged in d_out (dead until final GEMM overwrites it)
    transpose_kernel<<<dim3(n / 32, m / 32), dim3(32, 8), 0, stream>>>(X, out, m, n);
    mask_kernel<<<dim3(n / 256, m / 32), TPB, 0, stream>>>(X, s.maskV, s.maskU, m, n);

    for (int layer = 0; layer < 3; ++layer) {
        // V-step: q=n regressions (cols of X), D rows = U rows (Urow), beta = V cols
        hubreg(X,   s.maskV, s.Urow, s.Vc, s.Vrow, n, m, c, lamda, mu, sigma0, s, stream);
        // U-step: q=m regressions (rows of X), Y = XT, D rows = V cols (Vrow), beta = U rows
        hubreg(out, s.maskU, s.Vrow, s.Ut, s.Urow, m, n, c, lamda, mu, sigma0, s, stream);
    }

    gemm_kernel<<<dim3(n / TPB, m / ITILE), TPB, 0, stream>>>(s.Ut, s.Vc, out, m, n);
}